// Round 10
// baseline (212.254 us; speedup 1.0000x reference)
//
#include <hip/hip_runtime.h>
#include <hip/hip_bf16.h>
#include <math.h>

#define N_NODES 100000
#define N_EDGES 1600000
#define NF 128
#define NH 4
#define ND 16
#define GAT_ALPHA 0.2f

#define BSHIFT 8                      // bucket = dst >> 8 (256 nodes per bucket)
#define NBK 391                       // ceil(100000 / 256)
#define CAPB 5120                     // slab capacity per bucket (mean 4096 + 16 sigma)
#define CAPQ 1280                     // quarter-bucket LDS list capacity (mean 1024 + 8 sigma)
#define EPB 8192                      // edges per placement block
#define EBLK 196                      // placement blocks (ceil(E / EPB))
#define PBLK 391                      // projection blocks (4 tiles each — round-6 proven)
#define NTILES ((N_NODES + 63) / 64)  // 1563

typedef __attribute__((ext_vector_type(8))) __bf16 bf16x8;
typedef __attribute__((ext_vector_type(4))) float f32x4;

#define PADK 136                      // bf16 row stride (272B), breaks bank stride

// ---------------------------------------------------------------------------
// k_prep: one-time B-table build + gcur zeroing (replaces the memset launch).
// Btg layout (compact [80][128] bf16): rows 0..63 = W^T per head,
// rows 64+hh = W·a1, rows 72+hh = W·a2, rows 68..71 / 76..79 = zero.
// ---------------------------------------------------------------------------
__global__ __launch_bounds__(256) void k_prep(
    const float* __restrict__ W, const float* __restrict__ a,
    int* __restrict__ gcur, __hip_bfloat16* __restrict__ Btg)
{
    const int hh = blockIdx.x;        // 0..3 (one block per head)
    const int t = threadIdx.x;

    if (hh == 0)
        for (int i = t; i < 512; i += 256) gcur[i] = 0;

    // transpose W[hh] into rows hh*16+d
    for (int idx = t; idx < 2048; idx += 256) {
        int d = idx & 15, f = idx >> 4;
        Btg[(hh * 16 + d) * 128 + f] =
            __float2bfloat16(W[hh * (NF * ND) + f * ND + d]);
    }
    // dot rows: 64+hh (W·a1), 72+hh (W·a2)
    for (int idx = t; idx < 256; idx += 256) {
        int f = idx & 127, which = idx >> 7;
        float s = 0.f;
        #pragma unroll
        for (int d = 0; d < 16; d++)
            s = fmaf(W[hh * (NF * ND) + f * ND + d], a[hh * 32 + which * 16 + d], s);
        Btg[(64 + which * 8 + hh) * 128 + f] = __float2bfloat16(s);
    }
    // zero rows: 68+hh, 76+hh
    for (int idx = t; idx < 256; idx += 256) {
        int f = idx & 127, which = idx >> 7;
        Btg[(68 + which * 8 + hh) * 128 + f] = __float2bfloat16(0.f);
    }
}

// ---------------------------------------------------------------------------
// Fused kernel (round-6 proven config), role by blockIdx:
//   blocks [0, EBLK)      : bucket placement into 256-node slabs
//   blocks [EBLK, EBLK+PBLK): MFMA projection, 4 tiles/block, B staged by
//                           a 20.5 KB vectorized copy from precomputed Btg.
// ---------------------------------------------------------------------------
__global__ __launch_bounds__(256) void k_fused(
    const float* __restrict__ h, const __hip_bfloat16* __restrict__ Btg,
    const float* __restrict__ Wb, const float* __restrict__ a,
    const float* __restrict__ ab, const int* __restrict__ src,
    const int* __restrict__ dst, int* __restrict__ gcur,
    uint* __restrict__ sb, __hip_bfloat16* __restrict__ Whb,
    float* __restrict__ es, float* __restrict__ ed)
{
    __shared__ __align__(16) char smem[80 * PADK * 2];      // 21.8 KB union

    const int tid = threadIdx.x;

    if (blockIdx.x < EBLK) {
        // ---------------- role: bucket placement ------------------------
        int* hist = (int*)smem;            // [NBK]
        int* cur  = hist + NBK;            // [NBK]
        const int base = blockIdx.x * EPB;
        const int lim = min(EPB, N_EDGES - base);

        for (int i = tid; i < NBK; i += 256) hist[i] = 0;
        __syncthreads();
        for (int i = tid; i < lim; i += 256)
            atomicAdd(&hist[dst[base + i] >> BSHIFT], 1);
        __syncthreads();
        for (int i = tid; i < NBK; i += 256) {
            int v = hist[i];
            cur[i] = v ? atomicAdd(&gcur[i], v) : 0;
        }
        __syncthreads();
        for (int i = tid; i < lim; i += 256) {
            int d = dst[base + i];
            int bk = d >> BSHIFT;
            int pos = atomicAdd(&cur[bk], 1);            // LDS returning atomic
            if (pos < CAPB)
                sb[bk * CAPB + pos] = (uint)(src[base + i] | ((d & 255) << 17));
        }
        return;
    }

    // ------------------- role: MFMA projection --------------------------
    __hip_bfloat16* Bt = (__hip_bfloat16*)smem;   // [80][PADK]
    const int pb = blockIdx.x - EBLK;    // 0..PBLK-1
    const int wv = tid >> 6;
    const int l = tid & 63;
    const int m = l & 15;
    const int quad = l >> 4;

    // stage B: plain vectorized copy of precomputed table (1280 float4)
    for (int c = tid; c < 80 * 128 / 8; c += 256) {
        int row = c >> 4, col = (c & 15) * 8;
        *(float4*)&Bt[row * PADK + col] = ((const float4*)Btg)[c];
    }

    float wb4[4];
    #pragma unroll
    for (int t = 0; t < 4; t++) wb4[t] = Wb[t * 16 + m];
    float eb = 0.f;
    if (m < 4) {
        #pragma unroll
        for (int d = 0; d < 16; d++) eb = fmaf(Wb[m * 16 + d], a[m * 32 + d], eb);
    } else if (m >= 8 && m < 12) {
        int hh = m - 8;
        #pragma unroll
        for (int d = 0; d < 16; d++)
            eb = fmaf(Wb[hh * 16 + d], a[hh * 32 + 16 + d], eb);
        eb += ab[hh];
    }
    __syncthreads();   // Bt visible; no per-tile barriers needed after this

    for (int tile = pb; tile < NTILES; tile += PBLK) {
        const int node = tile * 64 + wv * 16 + m;   // A row this lane serves
        const bool ok = node < N_NODES;
        const float4* hrow = (const float4*)(h + (size_t)(ok ? node : 0) * NF);

        f32x4 acc[5];
        #pragma unroll
        for (int t = 0; t < 5; t++) acc[t] = (f32x4){0.f, 0.f, 0.f, 0.f};

        #pragma unroll
        for (int kk = 0; kk < 4; kk++) {
            // A-frag direct from global: cols kk*32 + quad*8 .. +8
            bf16x8 af;
            if (ok) {
                float4 v0 = hrow[kk * 8 + quad * 2];
                float4 v1 = hrow[kk * 8 + quad * 2 + 1];
                af[0] = (__bf16)v0.x; af[1] = (__bf16)v0.y;
                af[2] = (__bf16)v0.z; af[3] = (__bf16)v0.w;
                af[4] = (__bf16)v1.x; af[5] = (__bf16)v1.y;
                af[6] = (__bf16)v1.z; af[7] = (__bf16)v1.w;
            } else {
                #pragma unroll
                for (int j = 0; j < 8; j++) af[j] = (__bf16)0.f;
            }
            #pragma unroll
            for (int t = 0; t < 5; t++) {
                bf16x8 bf = *(const bf16x8*)&Bt[(t * 16 + m) * PADK + kk * 32 + quad * 8];
                acc[t] = __builtin_amdgcn_mfma_f32_16x16x32_bf16(af, bf, acc[t], 0, 0, 0);
            }
        }

        // epilogue: D layout col=lane&15, row=quad*4+reg
        const int nodeb = tile * 64 + wv * 16 + quad * 4;
        #pragma unroll
        for (int r = 0; r < 4; r++) {
            int n = nodeb + r;
            if (n < N_NODES) {
                #pragma unroll
                for (int t = 0; t < 4; t++)
                    Whb[n * 64 + t * 16 + m] = __float2bfloat16(acc[t][r] + wb4[t]);
                float ev = acc[4][r] + eb;
                if (m < 4) es[n * 4 + m] = ev;
                else if (m >= 8 && m < 12) ed[n * 4 + (m - 8)] = ev;
            }
        }
    }
}

// ---------------------------------------------------------------------------
// One block per QUARTER of a 256-node bucket (64 dst nodes, 256 thr, 4 waves).
// Count/scan/scatter phases unchanged (round-6 proven).  Gather phase
// RESTRUCTURED quarter-per-node: each wave processes 4 consecutive nodes per
// pass (their edges are contiguous in ssl).  Phase A stages exp() for the
// group's whole edge range densely (all 64 lanes, one es-latency per 4 nodes).
// Phase B: each 16-lane quarter owns one node, 1 edge/trip, lane-local
// accumulation -> denominator identical in all lanes -> NO shuffle reduce.
// ---------------------------------------------------------------------------
__global__ __launch_bounds__(256) void k_bucket(
    const uint* __restrict__ sb, const int* __restrict__ gcur,
    const __hip_bfloat16* __restrict__ Whb, const float* __restrict__ es,
    const float* __restrict__ ed, float* __restrict__ out)
{
    __shared__ int ssl[CAPQ];          // 5.1 KB node-grouped src list
    __shared__ int ncnt[64];           // per-node degree
    __shared__ int noff[64];           // per-node start in ssl
    __shared__ int ncur[64];           // scatter cursors
    __shared__ float edl[64 * 4];      // 1 KB ed rows for this block's nodes
    __shared__ float pu_all[4][256 * 4];  // 16 KB per-wave p staging (256 edges)

    const int b  = blockIdx.x >> 2;    // bucket
    const int qt = blockIdx.x & 3;     // quarter
    const int t  = threadIdx.x;
    const int l  = t & 63;
    const int wid = t >> 6;            // 0..3

    const int ebase = b * CAPB;
    const int ecnt = min(gcur[b], CAPB);
    const int dlo = qt << 6;           // 0,64,128,192

    if (t < 64) {
        ncnt[t] = 0;
        int node = b * 256 + dlo + t;
        ((float4*)edl)[t] = (node < N_NODES) ? ((const float4*)ed)[node]
                                             : make_float4(0.f, 0.f, 0.f, 0.f);
    }
    __syncthreads();

    // ---- count this quarter's nodes (filter; int LDS atomics) ----
    for (int i = t; i < ecnt; i += 256) {
        int dn = (int)(sb[ebase + i] >> 17) - dlo;
        if ((unsigned)dn < 64u) atomicAdd(&ncnt[dn], 1);
    }
    __syncthreads();

    // ---- inclusive scan of ncnt[0..63] by wave 0 ----
    if (t < 64) {
        int v = ncnt[t];
        int x = v;
        #pragma unroll
        for (int o = 1; o < 64; o <<= 1) {
            int y = __shfl_up(x, o);
            if (l >= o) x += y;
        }
        noff[t] = x - v;
        ncur[t] = x - v;
    }
    __syncthreads();

    // ---- scatter matching slab entries into node-grouped LDS list ----
    for (int i = t; i < ecnt; i += 256) {
        uint v = sb[ebase + i];
        int dn = (int)(v >> 17) - dlo;
        if ((unsigned)dn < 64u) {
            int pos = atomicAdd(&ncur[dn], 1);   // int returning LDS atomic
            if (pos < CAPQ) ssl[pos] = (int)(v & 0x1FFFFu);
        }
    }
    __syncthreads();

    // ---- gather phase: 4 waves x 4 groups of 4 nodes ----
    const int r = l & 15;              // dim quad within quarter: dims 4r..4r+3
    const int q = l >> 4;              // quarter = node-in-group
    const int hh = r >> 2;             // head of dims 4r..4r+3
    const float4* es4 = (const float4*)es;
    const uint2* Wu2 = (const uint2*)Whb;
    float* pu = &pu_all[wid][0];

    for (int kp = 0; kp < 4; kp++) {
        const int base = wid * 16 + kp * 4;   // first node-in-block of group

        int estart = min(noff[base], CAPQ);
        int eend = min(noff[base + 3] + ncnt[base + 3], CAPQ);
        int ecount = eend - estart;
        if (ecount < 0) ecount = 0;
        if (ecount > 256) ecount = 256;       // pu capacity (prob ~0)

        const int off1 = noff[base + 1], off2 = noff[base + 2], off3 = noff[base + 3];

        // phase A: dense exp staging for the whole group's edge range
        for (int e = l; e < ecount; e += 64) {
            int gi = estart + e;
            int sl = ssl[gi];
            int nid = (gi >= off1) + (gi >= off2) + (gi >= off3);
            const float4 edv = *(const float4*)&edl[(base + nid) * 4];
            float4 esv = es4[sl];
            float4 p4;
            float x;
            x = esv.x + edv.x; p4.x = __expf(fmaxf(x, GAT_ALPHA * x));
            x = esv.y + edv.y; p4.y = __expf(fmaxf(x, GAT_ALPHA * x));
            x = esv.z + edv.z; p4.z = __expf(fmaxf(x, GAT_ALPHA * x));
            x = esv.w + edv.w; p4.w = __expf(fmaxf(x, GAT_ALPHA * x));
            *(float4*)&pu[e * 4] = p4;
        }
        // single wave owns pu: wave-internal lgkm ordering, no barrier

        // phase B: quarter q owns node base+q; lane-local accumulation
        const int ln = base + q;
        const int sbase = noff[ln];
        int myoff = sbase - estart;
        int deg = ncnt[ln];
        if (sbase >= CAPQ) deg = 0;
        else deg = min(deg, CAPQ - sbase);
        {
            int pucap = ecount - myoff;
            if (pucap < 0) pucap = 0;
            deg = min(deg, pucap);
        }

        float a0 = 0.f, a1 = 0.f, a2 = 0.f, a3 = 0.f, den = 0.f;
        #pragma unroll 4
        for (int j = 0; j < deg; j++) {
            int s = ssl[sbase + j];
            float p = pu[(myoff + j) * 4 + hh];
            uint2 v = Wu2[s * 16 + r];
            a0 = fmaf(p, __uint_as_float(v.x << 16), a0);
            a1 = fmaf(p, __uint_as_float(v.x & 0xffff0000u), a1);
            a2 = fmaf(p, __uint_as_float(v.y << 16), a2);
            a3 = fmaf(p, __uint_as_float(v.y & 0xffff0000u), a3);
            den += p;
        }

        const int node = b * 256 + dlo + ln;
        if (node < N_NODES) {
            float rr = 1.0f / fmaxf(den, 1e-9f);   // deg==0 -> 0, matches ref
            ((float4*)out)[node * 16 + r] =
                make_float4(a0 * rr, a1 * rr, a2 * rr, a3 * rr);
        }
    }
}

// ---------------------------------------------------------------------------
extern "C" void kernel_launch(void* const* d_in, const int* in_sizes, int n_in,
                              void* d_out, int out_size, void* d_ws, size_t ws_size,
                              hipStream_t stream)
{
    const float* h  = (const float*)d_in[0];
    const float* W  = (const float*)d_in[1];
    const float* Wb = (const float*)d_in[2];
    const float* a  = (const float*)d_in[3];
    const float* ab = (const float*)d_in[4];
    const int* src  = (const int*)d_in[5];
    const int* dst  = (const int*)d_in[6];
    float* out = (float*)d_out;

    char* w = (char*)d_ws;
    __hip_bfloat16* Whb = (__hip_bfloat16*)w; w += (size_t)N_NODES * 64 * 2;  // 12.8 MB
    float* es      = (float*)w;  w += (size_t)N_NODES * 4 * 4;     // 1.6 MB
    float* ed      = (float*)w;  w += (size_t)N_NODES * 4 * 4;     // 1.6 MB
    uint* sb       = (uint*)w;   w += (size_t)NBK * CAPB * 4;      // 8.0 MB
    int* gcur      = (int*)w;    w += 512 * 4;
    __hip_bfloat16* Btg = (__hip_bfloat16*)w; w += 80 * 128 * 2;   // 20.5 KB
    // total ~24 MB

    k_prep<<<4, 256, 0, stream>>>(W, a, gcur, Btg);
    k_fused<<<EBLK + PBLK, 256, 0, stream>>>(h, Btg, Wb, a, ab, src, dst,
                                             gcur, sb, Whb, es, ed);
    k_bucket<<<NBK * 4, 256, 0, stream>>>(sb, gcur, Whb, es, ed, out);
}

// Round 11
// 200.512 us; speedup vs baseline: 1.0586x; 1.0586x over previous
//
#include <hip/hip_runtime.h>
#include <hip/hip_bf16.h>
#include <math.h>

#define N_NODES 100000
#define N_EDGES 1600000
#define NF 128
#define NH 4
#define ND 16
#define GAT_ALPHA 0.2f

#define BSHIFT 8                      // bucket = dst >> 8 (256 nodes per bucket)
#define NBK 391                       // ceil(100000 / 256)
#define CAPB 5120                     // slab capacity per bucket (mean 4096 + 16 sigma)
#define CAPQ 1280                     // quarter-bucket LDS list capacity (mean 1024 + 8 sigma)
#define EPB 8192                      // edges per placement block
#define EBLK 196                      // placement blocks (ceil(E / EPB))
#define PBLK 782                      // projection blocks (2 tiles each -> 3.8 blk/CU)
#define NTILES ((N_NODES + 63) / 64)  // 1563

typedef __attribute__((ext_vector_type(8))) __bf16 bf16x8;
typedef __attribute__((ext_vector_type(4))) float f32x4;

#define PADK 136                      // bf16 row stride (272B), breaks bank stride

// ---------------------------------------------------------------------------
// k_prep: one-time B-table build + gcur zeroing (replaces the memset launch).
// Btg layout (compact [80][128] bf16): rows 0..63 = W^T per head,
// rows 64+hh = W·a1, rows 72+hh = W·a2, rows 68..71 / 76..79 = zero.
// ---------------------------------------------------------------------------
__global__ __launch_bounds__(256) void k_prep(
    const float* __restrict__ W, const float* __restrict__ a,
    int* __restrict__ gcur, __hip_bfloat16* __restrict__ Btg)
{
    const int hh = blockIdx.x;        // 0..3 (one block per head)
    const int t = threadIdx.x;

    if (hh == 0)
        for (int i = t; i < 512; i += 256) gcur[i] = 0;

    // transpose W[hh] into rows hh*16+d
    for (int idx = t; idx < 2048; idx += 256) {
        int d = idx & 15, f = idx >> 4;
        Btg[(hh * 16 + d) * 128 + f] =
            __float2bfloat16(W[hh * (NF * ND) + f * ND + d]);
    }
    // dot rows: 64+hh (W·a1), 72+hh (W·a2)
    for (int idx = t; idx < 256; idx += 256) {
        int f = idx & 127, which = idx >> 7;
        float s = 0.f;
        #pragma unroll
        for (int d = 0; d < 16; d++)
            s = fmaf(W[hh * (NF * ND) + f * ND + d], a[hh * 32 + which * 16 + d], s);
        Btg[(64 + which * 8 + hh) * 128 + f] = __float2bfloat16(s);
    }
    // zero rows: 68+hh, 76+hh
    for (int idx = t; idx < 256; idx += 256) {
        int f = idx & 127, which = idx >> 7;
        Btg[(68 + which * 8 + hh) * 128 + f] = __float2bfloat16(0.f);
    }
}

// ---------------------------------------------------------------------------
// Fused kernel, role by blockIdx:
//   blocks [0, EBLK)      : bucket placement into 256-node slabs
//   blocks [EBLK, EBLK+PBLK): MFMA projection, 2 tiles/block (PBLK 782):
//   cheap Btg staging amortized over 2 tiles; 978 total blocks = 3.8/CU.
// ---------------------------------------------------------------------------
__global__ __launch_bounds__(256) void k_fused(
    const float* __restrict__ h, const __hip_bfloat16* __restrict__ Btg,
    const float* __restrict__ Wb, const float* __restrict__ a,
    const float* __restrict__ ab, const int* __restrict__ src,
    const int* __restrict__ dst, int* __restrict__ gcur,
    uint* __restrict__ sb, __hip_bfloat16* __restrict__ Whb,
    float* __restrict__ es, float* __restrict__ ed)
{
    __shared__ __align__(16) char smem[80 * PADK * 2];      // 21.8 KB union

    const int tid = threadIdx.x;

    if (blockIdx.x < EBLK) {
        // ---------------- role: bucket placement ------------------------
        int* hist = (int*)smem;            // [NBK]
        int* cur  = hist + NBK;            // [NBK]
        const int base = blockIdx.x * EPB;
        const int lim = min(EPB, N_EDGES - base);

        for (int i = tid; i < NBK; i += 256) hist[i] = 0;
        __syncthreads();
        for (int i = tid; i < lim; i += 256)
            atomicAdd(&hist[dst[base + i] >> BSHIFT], 1);
        __syncthreads();
        for (int i = tid; i < NBK; i += 256) {
            int v = hist[i];
            cur[i] = v ? atomicAdd(&gcur[i], v) : 0;
        }
        __syncthreads();
        for (int i = tid; i < lim; i += 256) {
            int d = dst[base + i];
            int bk = d >> BSHIFT;
            int pos = atomicAdd(&cur[bk], 1);            // LDS returning atomic
            if (pos < CAPB)
                sb[bk * CAPB + pos] = (uint)(src[base + i] | ((d & 255) << 17));
        }
        return;
    }

    // ------------------- role: MFMA projection --------------------------
    __hip_bfloat16* Bt = (__hip_bfloat16*)smem;   // [80][PADK]
    const int pb = blockIdx.x - EBLK;    // 0..PBLK-1
    const int wv = tid >> 6;
    const int l = tid & 63;
    const int m = l & 15;
    const int quad = l >> 4;

    // stage B: plain vectorized copy of precomputed table (1280 float4)
    for (int c = tid; c < 80 * 128 / 8; c += 256) {
        int row = c >> 4, col = (c & 15) * 8;
        *(float4*)&Bt[row * PADK + col] = ((const float4*)Btg)[c];
    }

    float wb4[4];
    #pragma unroll
    for (int t = 0; t < 4; t++) wb4[t] = Wb[t * 16 + m];
    float eb = 0.f;
    if (m < 4) {
        #pragma unroll
        for (int d = 0; d < 16; d++) eb = fmaf(Wb[m * 16 + d], a[m * 32 + d], eb);
    } else if (m >= 8 && m < 12) {
        int hh = m - 8;
        #pragma unroll
        for (int d = 0; d < 16; d++)
            eb = fmaf(Wb[hh * 16 + d], a[hh * 32 + 16 + d], eb);
        eb += ab[hh];
    }
    __syncthreads();   // Bt visible; no per-tile barriers needed after this

    for (int tile = pb; tile < NTILES; tile += PBLK) {
        const int node = tile * 64 + wv * 16 + m;   // A row this lane serves
        const bool ok = node < N_NODES;
        const float4* hrow = (const float4*)(h + (size_t)(ok ? node : 0) * NF);

        f32x4 acc[5];
        #pragma unroll
        for (int t = 0; t < 5; t++) acc[t] = (f32x4){0.f, 0.f, 0.f, 0.f};

        #pragma unroll
        for (int kk = 0; kk < 4; kk++) {
            // A-frag direct from global: cols kk*32 + quad*8 .. +8
            bf16x8 af;
            if (ok) {
                float4 v0 = hrow[kk * 8 + quad * 2];
                float4 v1 = hrow[kk * 8 + quad * 2 + 1];
                af[0] = (__bf16)v0.x; af[1] = (__bf16)v0.y;
                af[2] = (__bf16)v0.z; af[3] = (__bf16)v0.w;
                af[4] = (__bf16)v1.x; af[5] = (__bf16)v1.y;
                af[6] = (__bf16)v1.z; af[7] = (__bf16)v1.w;
            } else {
                #pragma unroll
                for (int j = 0; j < 8; j++) af[j] = (__bf16)0.f;
            }
            #pragma unroll
            for (int t = 0; t < 5; t++) {
                bf16x8 bf = *(const bf16x8*)&Bt[(t * 16 + m) * PADK + kk * 32 + quad * 8];
                acc[t] = __builtin_amdgcn_mfma_f32_16x16x32_bf16(af, bf, acc[t], 0, 0, 0);
            }
        }

        // epilogue: D layout col=lane&15, row=quad*4+reg
        const int nodeb = tile * 64 + wv * 16 + quad * 4;
        #pragma unroll
        for (int r = 0; r < 4; r++) {
            int n = nodeb + r;
            if (n < N_NODES) {
                #pragma unroll
                for (int t = 0; t < 4; t++)
                    Whb[n * 64 + t * 16 + m] = __float2bfloat16(acc[t][r] + wb4[t]);
                float ev = acc[4][r] + eb;
                if (m < 4) es[n * 4 + m] = ev;
                else if (m >= 8 && m < 12) ed[n * 4 + (m - 8)] = ev;
            }
        }
    }
}

// ---------------------------------------------------------------------------
// One block per QUARTER of a 256-node bucket (64 dst nodes, 256 thr, 4 waves,
// ~10 KB LDS): streams the full bucket slab, filters its quarter into a
// node-grouped LDS list (int atomics), then sequential-FMA per-node gather.
// ROUND-6 EXACT SOURCE (measured 59.2-59.7 µs; uint4, quarter-per-node, and
// dense-staging restructures all regressed — this is the local optimum).
// ---------------------------------------------------------------------------
__global__ __launch_bounds__(256) void k_bucket(
    const uint* __restrict__ sb, const int* __restrict__ gcur,
    const __hip_bfloat16* __restrict__ Whb, const float* __restrict__ es,
    const float* __restrict__ ed, float* __restrict__ out)
{
    __shared__ int ssl[CAPQ];          // 5.1 KB node-grouped src list
    __shared__ int ncnt[64];           // per-node degree
    __shared__ int noff[64];           // per-node start in ssl
    __shared__ int ncur[64];           // scatter cursors
    __shared__ float pu_all[4][256];   // 4 KB per-wave p staging

    const int b  = blockIdx.x >> 2;    // bucket
    const int qt = blockIdx.x & 3;     // quarter
    const int t  = threadIdx.x;
    const int l  = t & 63;
    const int wid = t >> 6;            // 0..3

    const int ebase = b * CAPB;
    const int ecnt = min(gcur[b], CAPB);
    const int dlo = qt << 6;           // 0,64,128,192

    if (t < 64) ncnt[t] = 0;
    __syncthreads();

    // ---- count this quarter's nodes (filter; int LDS atomics) ----
    for (int i = t; i < ecnt; i += 256) {
        int dn = (int)(sb[ebase + i] >> 17) - dlo;
        if ((unsigned)dn < 64u) atomicAdd(&ncnt[dn], 1);
    }
    __syncthreads();

    // ---- inclusive scan of ncnt[0..63] by wave 0 ----
    if (t < 64) {
        int v = ncnt[t];
        int x = v;
        #pragma unroll
        for (int o = 1; o < 64; o <<= 1) {
            int y = __shfl_up(x, o);
            if (l >= o) x += y;
        }
        noff[t] = x - v;
        ncur[t] = x - v;
    }
    __syncthreads();

    // ---- scatter matching slab entries into node-grouped LDS list ----
    for (int i = t; i < ecnt; i += 256) {
        uint v = sb[ebase + i];
        int dn = (int)(v >> 17) - dlo;
        if ((unsigned)dn < 64u) {
            int pos = atomicAdd(&ncur[dn], 1);   // int returning LDS atomic
            if (pos < CAPQ) ssl[pos] = (int)(v & 0x1FFFFu);
        }
    }
    __syncthreads();

    // ---- gather phase: 4 waves x 16 nodes, sequential-FMA inner loop ----
    const int r = l & 15;              // lane-in-quarter: dims 4r..4r+3
    const int q = l >> 4;              // quarter-wave = which edge of the 4-group
    const int hh = r >> 2;             // head of dims 4r..4r+3
    const float4* es4 = (const float4*)es;
    const uint2* Wu2 = (const uint2*)Whb;
    float* pu = &pu_all[wid][0];
    const float* pu_q = pu + q * 4 + hh;

    for (int k = 0; k < 16; k++) {
        const int ln = wid * 16 + k;
        const int node = b * 256 + dlo + ln;
        if (node >= N_NODES) break;    // nodes ascend within wave

        int start = noff[ln];
        int deg = ncnt[ln];
        if (start >= CAPQ) deg = 0;            // overflow-drop safety
        else deg = min(deg, CAPQ - start);

        const float4 edv = ((const float4*)ed)[node];

        float acc0 = 0.f, acc1 = 0.f, acc2 = 0.f, acc3 = 0.f, den = 0.f;

        for (int bst = 0; bst < deg; bst += 64) {
            int nchunk = min(64, deg - bst);

            float4 p4 = make_float4(0.f, 0.f, 0.f, 0.f);
            if (l < nchunk) {
                int sl = ssl[start + bst + l];
                float4 esv = es4[sl];
                float x;
                x = esv.x + edv.x; p4.x = __expf(fmaxf(x, GAT_ALPHA * x));
                x = esv.y + edv.y; p4.y = __expf(fmaxf(x, GAT_ALPHA * x));
                x = esv.z + edv.z; p4.z = __expf(fmaxf(x, GAT_ALPHA * x));
                x = esv.w + edv.w; p4.w = __expf(fmaxf(x, GAT_ALPHA * x));
            }
            ((float4*)pu)[l] = p4;     // zero-padded tail
            // single wave owns pu: wave-internal lgkm ordering, no barrier

            const int last = start + deg - 1;
            #pragma unroll 4
            for (int jj = 0; jj < nchunk; jj += 4) {
                int ee = min(start + bst + jj + q, last);  // clamp: tail p==0
                int s = ssl[ee];
                float p = pu_q[jj * 4];
                uint2 v = Wu2[s * 16 + r];
                acc0 = fmaf(p, __uint_as_float(v.x << 16), acc0);
                acc1 = fmaf(p, __uint_as_float(v.x & 0xffff0000u), acc1);
                acc2 = fmaf(p, __uint_as_float(v.y << 16), acc2);
                acc3 = fmaf(p, __uint_as_float(v.y & 0xffff0000u), acc3);
                den += p;
            }
        }

        acc0 += __shfl_xor(acc0, 16); acc1 += __shfl_xor(acc1, 16);
        acc2 += __shfl_xor(acc2, 16); acc3 += __shfl_xor(acc3, 16);
        den  += __shfl_xor(den, 16);
        acc0 += __shfl_xor(acc0, 32); acc1 += __shfl_xor(acc1, 32);
        acc2 += __shfl_xor(acc2, 32); acc3 += __shfl_xor(acc3, 32);
        den  += __shfl_xor(den, 32);

        if (q == 0) {
            float rr = 1.0f / fmaxf(den, 1e-9f);   // deg==0 -> 0, matches ref
            ((float4*)out)[node * 16 + r] =
                make_float4(acc0 * rr, acc1 * rr, acc2 * rr, acc3 * rr);
        }
    }
}

// ---------------------------------------------------------------------------
extern "C" void kernel_launch(void* const* d_in, const int* in_sizes, int n_in,
                              void* d_out, int out_size, void* d_ws, size_t ws_size,
                              hipStream_t stream)
{
    const float* h  = (const float*)d_in[0];
    const float* W  = (const float*)d_in[1];
    const float* Wb = (const float*)d_in[2];
    const float* a  = (const float*)d_in[3];
    const float* ab = (const float*)d_in[4];
    const int* src  = (const int*)d_in[5];
    const int* dst  = (const int*)d_in[6];
    float* out = (float*)d_out;

    char* w = (char*)d_ws;
    __hip_bfloat16* Whb = (__hip_bfloat16*)w; w += (size_t)N_NODES * 64 * 2;  // 12.8 MB
    float* es      = (float*)w;  w += (size_t)N_NODES * 4 * 4;     // 1.6 MB
    float* ed      = (float*)w;  w += (size_t)N_NODES * 4 * 4;     // 1.6 MB
    uint* sb       = (uint*)w;   w += (size_t)NBK * CAPB * 4;      // 8.0 MB
    int* gcur      = (int*)w;    w += 512 * 4;
    __hip_bfloat16* Btg = (__hip_bfloat16*)w; w += 80 * 128 * 2;   // 20.5 KB
    // total ~24 MB

    k_prep<<<4, 256, 0, stream>>>(W, a, gcur, Btg);
    k_fused<<<EBLK + PBLK, 256, 0, stream>>>(h, Btg, Wb, a, ab, src, dst,
                                             gcur, sb, Whb, es, ed);
    k_bucket<<<NBK * 4, 256, 0, stream>>>(sb, gcur, Whb, es, ed, out);
}

// Round 12
// 199.503 us; speedup vs baseline: 1.0639x; 1.0051x over previous
//
#include <hip/hip_runtime.h>
#include <hip/hip_bf16.h>
#include <hip/hip_cooperative_groups.h>
#include <math.h>

namespace cg = cooperative_groups;

#define N_NODES 100000
#define N_EDGES 1600000
#define NF 128
#define NH 4
#define ND 16
#define GAT_ALPHA 0.2f

#define BSHIFT 8                      // bucket = dst >> 8 (256 nodes per bucket)
#define NBK 391                       // ceil(100000 / 256)
#define CAPB 5120                     // slab capacity per bucket
#define CAPQ 1280                     // quarter-bucket LDS list capacity
#define EPB 8192                      // edges per placement block
#define EBLK 196                      // placement blocks
#define PBLK 391                      // projection blocks (4 tiles each — proven)
#define NTILES ((N_NODES + 63) / 64)  // 1563
#define GRID_ALL (NBK * 4)            // 1564

typedef __attribute__((ext_vector_type(8))) __bf16 bf16x8;
typedef __attribute__((ext_vector_type(4))) float f32x4;

#define PADK 136                      // bf16 row stride (272B), breaks bank stride

// ===========================================================================
// MERGED cooperative kernel: phase0 prep -> sync -> phase1 place||project ->
// sync -> phase2 gather.  All phase bodies are the round-6-proven code.
// __launch_bounds__(256,8) caps VGPR at 64 so 7 blocks/CU fit (LDS 21.8KB),
// 7*256=1792 >= 1564 co-resident blocks required by grid.sync().
// ===========================================================================
__global__ __launch_bounds__(256, 8) void k_all(
    const float* __restrict__ h, const float* __restrict__ W,
    const float* __restrict__ Wb, const float* __restrict__ a,
    const float* __restrict__ ab, const int* __restrict__ src,
    const int* __restrict__ dst, int* __restrict__ gcur,
    uint* __restrict__ sb, __hip_bfloat16* __restrict__ Whb,
    float* __restrict__ es, float* __restrict__ ed,
    __hip_bfloat16* __restrict__ Btg, float* __restrict__ out)
{
    cg::grid_group grid = cg::this_grid();
    __shared__ __align__(16) char smem[80 * PADK * 2];      // 21.8 KB union

    const int tid = threadIdx.x;
    const int bid = blockIdx.x;
    const int l = tid & 63;
    const int wid = tid >> 6;

    // ---------------- phase 0: B-table prep + gcur zero (4 blocks) --------
    if (bid < 4) {
        const int hh = bid;
        if (hh == 0)
            for (int i = tid; i < 512; i += 256) gcur[i] = 0;
        for (int idx = tid; idx < 2048; idx += 256) {
            int d = idx & 15, f = idx >> 4;
            Btg[(hh * 16 + d) * 128 + f] =
                __float2bfloat16(W[hh * (NF * ND) + f * ND + d]);
        }
        for (int idx = tid; idx < 256; idx += 256) {
            int f = idx & 127, which = idx >> 7;
            float s = 0.f;
            #pragma unroll
            for (int d = 0; d < 16; d++)
                s = fmaf(W[hh * (NF * ND) + f * ND + d],
                         a[hh * 32 + which * 16 + d], s);
            Btg[(64 + which * 8 + hh) * 128 + f] = __float2bfloat16(s);
        }
        for (int idx = tid; idx < 256; idx += 256) {
            int f = idx & 127, which = idx >> 7;
            Btg[(68 + which * 8 + hh) * 128 + f] = __float2bfloat16(0.f);
        }
    }
    grid.sync();

    // ---------------- phase 1: placement || projection --------------------
    if (bid < EBLK) {
        // role: bucket placement (round-6 body)
        int* hist = (int*)smem;
        int* cur  = hist + NBK;
        const int base = bid * EPB;
        const int lim = min(EPB, N_EDGES - base);

        for (int i = tid; i < NBK; i += 256) hist[i] = 0;
        __syncthreads();
        for (int i = tid; i < lim; i += 256)
            atomicAdd(&hist[dst[base + i] >> BSHIFT], 1);
        __syncthreads();
        for (int i = tid; i < NBK; i += 256) {
            int v = hist[i];
            cur[i] = v ? atomicAdd(&gcur[i], v) : 0;
        }
        __syncthreads();
        for (int i = tid; i < lim; i += 256) {
            int d = dst[base + i];
            int bk = d >> BSHIFT;
            int pos = atomicAdd(&cur[bk], 1);            // LDS returning atomic
            if (pos < CAPB)
                sb[bk * CAPB + pos] = (uint)(src[base + i] | ((d & 255) << 17));
        }
    } else if (bid < EBLK + PBLK) {
        // role: MFMA projection, 4 tiles/block (round-6 body)
        __hip_bfloat16* Bt = (__hip_bfloat16*)smem;
        const int pb = bid - EBLK;
        const int m = l & 15;
        const int quad = l >> 4;

        for (int c = tid; c < 80 * 128 / 8; c += 256) {
            int row = c >> 4, col = (c & 15) * 8;
            *(float4*)&Bt[row * PADK + col] = ((const float4*)Btg)[c];
        }

        float wb4[4];
        #pragma unroll
        for (int t = 0; t < 4; t++) wb4[t] = Wb[t * 16 + m];
        float eb = 0.f;
        if (m < 4) {
            #pragma unroll
            for (int d = 0; d < 16; d++)
                eb = fmaf(Wb[m * 16 + d], a[m * 32 + d], eb);
        } else if (m >= 8 && m < 12) {
            int hh = m - 8;
            #pragma unroll
            for (int d = 0; d < 16; d++)
                eb = fmaf(Wb[hh * 16 + d], a[hh * 32 + 16 + d], eb);
            eb += ab[hh];
        }
        __syncthreads();   // Bt visible

        for (int tile = pb; tile < NTILES; tile += PBLK) {
            const int node = tile * 64 + wid * 16 + m;
            const bool ok = node < N_NODES;
            const float4* hrow =
                (const float4*)(h + (size_t)(ok ? node : 0) * NF);

            f32x4 acc[5];
            #pragma unroll
            for (int t = 0; t < 5; t++) acc[t] = (f32x4){0.f, 0.f, 0.f, 0.f};

            #pragma unroll
            for (int kk = 0; kk < 4; kk++) {
                bf16x8 af;
                if (ok) {
                    float4 v0 = hrow[kk * 8 + quad * 2];
                    float4 v1 = hrow[kk * 8 + quad * 2 + 1];
                    af[0] = (__bf16)v0.x; af[1] = (__bf16)v0.y;
                    af[2] = (__bf16)v0.z; af[3] = (__bf16)v0.w;
                    af[4] = (__bf16)v1.x; af[5] = (__bf16)v1.y;
                    af[6] = (__bf16)v1.z; af[7] = (__bf16)v1.w;
                } else {
                    #pragma unroll
                    for (int j = 0; j < 8; j++) af[j] = (__bf16)0.f;
                }
                #pragma unroll
                for (int t = 0; t < 5; t++) {
                    bf16x8 bf = *(const bf16x8*)
                        &Bt[(t * 16 + m) * PADK + kk * 32 + quad * 8];
                    acc[t] = __builtin_amdgcn_mfma_f32_16x16x32_bf16(
                        af, bf, acc[t], 0, 0, 0);
                }
            }

            const int nodeb = tile * 64 + wid * 16 + quad * 4;
            #pragma unroll
            for (int r = 0; r < 4; r++) {
                int n = nodeb + r;
                if (n < N_NODES) {
                    #pragma unroll
                    for (int t = 0; t < 4; t++)
                        Whb[n * 64 + t * 16 + m] =
                            __float2bfloat16(acc[t][r] + wb4[t]);
                    float ev = acc[4][r] + eb;
                    if (m < 4) es[n * 4 + m] = ev;
                    else if (m >= 8 && m < 12) ed[n * 4 + (m - 8)] = ev;
                }
            }
        }
    }
    grid.sync();

    // ---------------- phase 2: quarter-bucket gather (round-6 body) -------
    {
        int* ssl  = (int*)smem;               // CAPQ ints (5.1 KB)
        int* ncnt = ssl + CAPQ;
        int* noff = ncnt + 64;
        int* ncur = noff + 64;
        float* pu_all = (float*)(ncur + 64);  // [4][256] floats (4 KB)

        const int b  = bid >> 2;
        const int qt = bid & 3;

        const int ebase = b * CAPB;
        const int ecnt = min(gcur[b], CAPB);
        const int dlo = qt << 6;

        if (tid < 64) ncnt[tid] = 0;
        __syncthreads();

        for (int i = tid; i < ecnt; i += 256) {
            int dn = (int)(sb[ebase + i] >> 17) - dlo;
            if ((unsigned)dn < 64u) atomicAdd(&ncnt[dn], 1);
        }
        __syncthreads();

        if (tid < 64) {
            int v = ncnt[tid];
            int x = v;
            #pragma unroll
            for (int o = 1; o < 64; o <<= 1) {
                int y = __shfl_up(x, o);
                if (l >= o) x += y;
            }
            noff[tid] = x - v;
            ncur[tid] = x - v;
        }
        __syncthreads();

        for (int i = tid; i < ecnt; i += 256) {
            uint v = sb[ebase + i];
            int dn = (int)(v >> 17) - dlo;
            if ((unsigned)dn < 64u) {
                int pos = atomicAdd(&ncur[dn], 1);
                if (pos < CAPQ) ssl[pos] = (int)(v & 0x1FFFFu);
            }
        }
        __syncthreads();

        const int r = l & 15;
        const int q = l >> 4;
        const int hh = r >> 2;
        const float4* es4 = (const float4*)es;
        const uint2* Wu2 = (const uint2*)Whb;
        float* pu = pu_all + wid * 256;
        const float* pu_q = pu + q * 4 + hh;

        for (int k = 0; k < 16; k++) {
            const int ln = wid * 16 + k;
            const int node = b * 256 + dlo + ln;
            if (node >= N_NODES) break;

            int start = noff[ln];
            int deg = ncnt[ln];
            if (start >= CAPQ) deg = 0;
            else deg = min(deg, CAPQ - start);

            const float4 edv = ((const float4*)ed)[node];

            float acc0 = 0.f, acc1 = 0.f, acc2 = 0.f, acc3 = 0.f, den = 0.f;

            for (int bst = 0; bst < deg; bst += 64) {
                int nchunk = min(64, deg - bst);

                float4 p4 = make_float4(0.f, 0.f, 0.f, 0.f);
                if (l < nchunk) {
                    int sl = ssl[start + bst + l];
                    float4 esv = es4[sl];
                    float x;
                    x = esv.x + edv.x; p4.x = __expf(fmaxf(x, GAT_ALPHA * x));
                    x = esv.y + edv.y; p4.y = __expf(fmaxf(x, GAT_ALPHA * x));
                    x = esv.z + edv.z; p4.z = __expf(fmaxf(x, GAT_ALPHA * x));
                    x = esv.w + edv.w; p4.w = __expf(fmaxf(x, GAT_ALPHA * x));
                }
                ((float4*)pu)[l] = p4;
                // single wave owns pu: wave-internal lgkm ordering, no barrier

                const int last = start + deg - 1;
                #pragma unroll 4
                for (int jj = 0; jj < nchunk; jj += 4) {
                    int ee = min(start + bst + jj + q, last);
                    int s = ssl[ee];
                    float p = pu_q[jj * 4];
                    uint2 v = Wu2[s * 16 + r];
                    acc0 = fmaf(p, __uint_as_float(v.x << 16), acc0);
                    acc1 = fmaf(p, __uint_as_float(v.x & 0xffff0000u), acc1);
                    acc2 = fmaf(p, __uint_as_float(v.y << 16), acc2);
                    acc3 = fmaf(p, __uint_as_float(v.y & 0xffff0000u), acc3);
                    den += p;
                }
            }

            acc0 += __shfl_xor(acc0, 16); acc1 += __shfl_xor(acc1, 16);
            acc2 += __shfl_xor(acc2, 16); acc3 += __shfl_xor(acc3, 16);
            den  += __shfl_xor(den, 16);
            acc0 += __shfl_xor(acc0, 32); acc1 += __shfl_xor(acc1, 32);
            acc2 += __shfl_xor(acc2, 32); acc3 += __shfl_xor(acc3, 32);
            den  += __shfl_xor(den, 32);

            if (q == 0) {
                float rr = 1.0f / fmaxf(den, 1e-9f);
                ((float4*)out)[node * 16 + r] =
                    make_float4(acc0 * rr, acc1 * rr, acc2 * rr, acc3 * rr);
            }
        }
    }
}

// ===========================================================================
// Fallback path: the proven round-6 three-kernel pipeline (192.9 µs), used
// if cooperative occupancy/launch is unavailable.
// ===========================================================================
__global__ __launch_bounds__(256) void k_prep(
    const float* __restrict__ W, const float* __restrict__ a,
    int* __restrict__ gcur, __hip_bfloat16* __restrict__ Btg)
{
    const int hh = blockIdx.x;
    const int t = threadIdx.x;

    if (hh == 0)
        for (int i = t; i < 512; i += 256) gcur[i] = 0;

    for (int idx = t; idx < 2048; idx += 256) {
        int d = idx & 15, f = idx >> 4;
        Btg[(hh * 16 + d) * 128 + f] =
            __float2bfloat16(W[hh * (NF * ND) + f * ND + d]);
    }
    for (int idx = t; idx < 256; idx += 256) {
        int f = idx & 127, which = idx >> 7;
        float s = 0.f;
        #pragma unroll
        for (int d = 0; d < 16; d++)
            s = fmaf(W[hh * (NF * ND) + f * ND + d], a[hh * 32 + which * 16 + d], s);
        Btg[(64 + which * 8 + hh) * 128 + f] = __float2bfloat16(s);
    }
    for (int idx = t; idx < 256; idx += 256) {
        int f = idx & 127, which = idx >> 7;
        Btg[(68 + which * 8 + hh) * 128 + f] = __float2bfloat16(0.f);
    }
}

__global__ __launch_bounds__(256) void k_fused(
    const float* __restrict__ h, const __hip_bfloat16* __restrict__ Btg,
    const float* __restrict__ Wb, const float* __restrict__ a,
    const float* __restrict__ ab, const int* __restrict__ src,
    const int* __restrict__ dst, int* __restrict__ gcur,
    uint* __restrict__ sb, __hip_bfloat16* __restrict__ Whb,
    float* __restrict__ es, float* __restrict__ ed)
{
    __shared__ __align__(16) char smem[80 * PADK * 2];

    const int tid = threadIdx.x;

    if (blockIdx.x < EBLK) {
        int* hist = (int*)smem;
        int* cur  = hist + NBK;
        const int base = blockIdx.x * EPB;
        const int lim = min(EPB, N_EDGES - base);

        for (int i = tid; i < NBK; i += 256) hist[i] = 0;
        __syncthreads();
        for (int i = tid; i < lim; i += 256)
            atomicAdd(&hist[dst[base + i] >> BSHIFT], 1);
        __syncthreads();
        for (int i = tid; i < NBK; i += 256) {
            int v = hist[i];
            cur[i] = v ? atomicAdd(&gcur[i], v) : 0;
        }
        __syncthreads();
        for (int i = tid; i < lim; i += 256) {
            int d = dst[base + i];
            int bk = d >> BSHIFT;
            int pos = atomicAdd(&cur[bk], 1);
            if (pos < CAPB)
                sb[bk * CAPB + pos] = (uint)(src[base + i] | ((d & 255) << 17));
        }
        return;
    }

    __hip_bfloat16* Bt = (__hip_bfloat16*)smem;
    const int pb = blockIdx.x - EBLK;
    const int wv = tid >> 6;
    const int l = tid & 63;
    const int m = l & 15;
    const int quad = l >> 4;

    for (int c = tid; c < 80 * 128 / 8; c += 256) {
        int row = c >> 4, col = (c & 15) * 8;
        *(float4*)&Bt[row * PADK + col] = ((const float4*)Btg)[c];
    }

    float wb4[4];
    #pragma unroll
    for (int t = 0; t < 4; t++) wb4[t] = Wb[t * 16 + m];
    float eb = 0.f;
    if (m < 4) {
        #pragma unroll
        for (int d = 0; d < 16; d++) eb = fmaf(Wb[m * 16 + d], a[m * 32 + d], eb);
    } else if (m >= 8 && m < 12) {
        int hh = m - 8;
        #pragma unroll
        for (int d = 0; d < 16; d++)
            eb = fmaf(Wb[hh * 16 + d], a[hh * 32 + 16 + d], eb);
        eb += ab[hh];
    }
    __syncthreads();

    for (int tile = pb; tile < NTILES; tile += PBLK) {
        const int node = tile * 64 + wv * 16 + m;
        const bool ok = node < N_NODES;
        const float4* hrow = (const float4*)(h + (size_t)(ok ? node : 0) * NF);

        f32x4 acc[5];
        #pragma unroll
        for (int t = 0; t < 5; t++) acc[t] = (f32x4){0.f, 0.f, 0.f, 0.f};

        #pragma unroll
        for (int kk = 0; kk < 4; kk++) {
            bf16x8 af;
            if (ok) {
                float4 v0 = hrow[kk * 8 + quad * 2];
                float4 v1 = hrow[kk * 8 + quad * 2 + 1];
                af[0] = (__bf16)v0.x; af[1] = (__bf16)v0.y;
                af[2] = (__bf16)v0.z; af[3] = (__bf16)v0.w;
                af[4] = (__bf16)v1.x; af[5] = (__bf16)v1.y;
                af[6] = (__bf16)v1.z; af[7] = (__bf16)v1.w;
            } else {
                #pragma unroll
                for (int j = 0; j < 8; j++) af[j] = (__bf16)0.f;
            }
            #pragma unroll
            for (int t = 0; t < 5; t++) {
                bf16x8 bf = *(const bf16x8*)&Bt[(t * 16 + m) * PADK + kk * 32 + quad * 8];
                acc[t] = __builtin_amdgcn_mfma_f32_16x16x32_bf16(af, bf, acc[t], 0, 0, 0);
            }
        }

        const int nodeb = tile * 64 + wv * 16 + quad * 4;
        #pragma unroll
        for (int r = 0; r < 4; r++) {
            int n = nodeb + r;
            if (n < N_NODES) {
                #pragma unroll
                for (int t = 0; t < 4; t++)
                    Whb[n * 64 + t * 16 + m] = __float2bfloat16(acc[t][r] + wb4[t]);
                float ev = acc[4][r] + eb;
                if (m < 4) es[n * 4 + m] = ev;
                else if (m >= 8 && m < 12) ed[n * 4 + (m - 8)] = ev;
            }
        }
    }
}

__global__ __launch_bounds__(256) void k_bucket(
    const uint* __restrict__ sb, const int* __restrict__ gcur,
    const __hip_bfloat16* __restrict__ Whb, const float* __restrict__ es,
    const float* __restrict__ ed, float* __restrict__ out)
{
    __shared__ int ssl[CAPQ];
    __shared__ int ncnt[64];
    __shared__ int noff[64];
    __shared__ int ncur[64];
    __shared__ float pu_all[4][256];

    const int b  = blockIdx.x >> 2;
    const int qt = blockIdx.x & 3;
    const int t  = threadIdx.x;
    const int l  = t & 63;
    const int wid = t >> 6;

    const int ebase = b * CAPB;
    const int ecnt = min(gcur[b], CAPB);
    const int dlo = qt << 6;

    if (t < 64) ncnt[t] = 0;
    __syncthreads();

    for (int i = t; i < ecnt; i += 256) {
        int dn = (int)(sb[ebase + i] >> 17) - dlo;
        if ((unsigned)dn < 64u) atomicAdd(&ncnt[dn], 1);
    }
    __syncthreads();

    if (t < 64) {
        int v = ncnt[t];
        int x = v;
        #pragma unroll
        for (int o = 1; o < 64; o <<= 1) {
            int y = __shfl_up(x, o);
            if (l >= o) x += y;
        }
        noff[t] = x - v;
        ncur[t] = x - v;
    }
    __syncthreads();

    for (int i = t; i < ecnt; i += 256) {
        uint v = sb[ebase + i];
        int dn = (int)(v >> 17) - dlo;
        if ((unsigned)dn < 64u) {
            int pos = atomicAdd(&ncur[dn], 1);
            if (pos < CAPQ) ssl[pos] = (int)(v & 0x1FFFFu);
        }
    }
    __syncthreads();

    const int r = l & 15;
    const int q = l >> 4;
    const int hh = r >> 2;
    const float4* es4 = (const float4*)es;
    const uint2* Wu2 = (const uint2*)Whb;
    float* pu = &pu_all[wid][0];
    const float* pu_q = pu + q * 4 + hh;

    for (int k = 0; k < 16; k++) {
        const int ln = wid * 16 + k;
        const int node = b * 256 + dlo + ln;
        if (node >= N_NODES) break;

        int start = noff[ln];
        int deg = ncnt[ln];
        if (start >= CAPQ) deg = 0;
        else deg = min(deg, CAPQ - start);

        const float4 edv = ((const float4*)ed)[node];

        float acc0 = 0.f, acc1 = 0.f, acc2 = 0.f, acc3 = 0.f, den = 0.f;

        for (int bst = 0; bst < deg; bst += 64) {
            int nchunk = min(64, deg - bst);

            float4 p4 = make_float4(0.f, 0.f, 0.f, 0.f);
            if (l < nchunk) {
                int sl = ssl[start + bst + l];
                float4 esv = es4[sl];
                float x;
                x = esv.x + edv.x; p4.x = __expf(fmaxf(x, GAT_ALPHA * x));
                x = esv.y + edv.y; p4.y = __expf(fmaxf(x, GAT_ALPHA * x));
                x = esv.z + edv.z; p4.z = __expf(fmaxf(x, GAT_ALPHA * x));
                x = esv.w + edv.w; p4.w = __expf(fmaxf(x, GAT_ALPHA * x));
            }
            ((float4*)pu)[l] = p4;

            const int last = start + deg - 1;
            #pragma unroll 4
            for (int jj = 0; jj < nchunk; jj += 4) {
                int ee = min(start + bst + jj + q, last);
                int s = ssl[ee];
                float p = pu_q[jj * 4];
                uint2 v = Wu2[s * 16 + r];
                acc0 = fmaf(p, __uint_as_float(v.x << 16), acc0);
                acc1 = fmaf(p, __uint_as_float(v.x & 0xffff0000u), acc1);
                acc2 = fmaf(p, __uint_as_float(v.y << 16), acc2);
                acc3 = fmaf(p, __uint_as_float(v.y & 0xffff0000u), acc3);
                den += p;
            }
        }

        acc0 += __shfl_xor(acc0, 16); acc1 += __shfl_xor(acc1, 16);
        acc2 += __shfl_xor(acc2, 16); acc3 += __shfl_xor(acc3, 16);
        den  += __shfl_xor(den, 16);
        acc0 += __shfl_xor(acc0, 32); acc1 += __shfl_xor(acc1, 32);
        acc2 += __shfl_xor(acc2, 32); acc3 += __shfl_xor(acc3, 32);
        den  += __shfl_xor(den, 32);

        if (q == 0) {
            float rr = 1.0f / fmaxf(den, 1e-9f);
            ((float4*)out)[node * 16 + r] =
                make_float4(acc0 * rr, acc1 * rr, acc2 * rr, acc3 * rr);
        }
    }
}

// ---------------------------------------------------------------------------
extern "C" void kernel_launch(void* const* d_in, const int* in_sizes, int n_in,
                              void* d_out, int out_size, void* d_ws, size_t ws_size,
                              hipStream_t stream)
{
    const float* h  = (const float*)d_in[0];
    const float* W  = (const float*)d_in[1];
    const float* Wb = (const float*)d_in[2];
    const float* a  = (const float*)d_in[3];
    const float* ab = (const float*)d_in[4];
    const int* src  = (const int*)d_in[5];
    const int* dst  = (const int*)d_in[6];
    float* out = (float*)d_out;

    char* w = (char*)d_ws;
    __hip_bfloat16* Whb = (__hip_bfloat16*)w; w += (size_t)N_NODES * 64 * 2;  // 12.8 MB
    float* es      = (float*)w;  w += (size_t)N_NODES * 4 * 4;     // 1.6 MB
    float* ed      = (float*)w;  w += (size_t)N_NODES * 4 * 4;     // 1.6 MB
    uint* sb       = (uint*)w;   w += (size_t)NBK * CAPB * 4;      // 8.0 MB
    int* gcur      = (int*)w;    w += 512 * 4;
    __hip_bfloat16* Btg = (__hip_bfloat16*)w; w += 80 * 128 * 2;   // 20.5 KB
    // total ~24 MB

    // one-time: can the merged cooperative kernel be fully co-resident?
    static int use_coop = -1;
    if (use_coop < 0) {
        int nb = 0;
        hipError_t e = hipOccupancyMaxActiveBlocksPerMultiprocessor(
            &nb, k_all, 256, 0);
        use_coop = (e == hipSuccess && (long)nb * 256 >= GRID_ALL) ? 1 : 0;
    }

    if (use_coop) {
        void* args[] = {
            (void*)&h, (void*)&W, (void*)&Wb, (void*)&a, (void*)&ab,
            (void*)&src, (void*)&dst, (void*)&gcur, (void*)&sb,
            (void*)&Whb, (void*)&es, (void*)&ed, (void*)&Btg, (void*)&out};
        hipError_t le = hipLaunchCooperativeKernel(
            reinterpret_cast<void*>(k_all), dim3(GRID_ALL), dim3(256),
            args, 0, stream);
        if (le == hipSuccess) return;
        use_coop = 0;   // launch refused -> fall through to proven 3-kernel path
    }

    k_prep<<<4, 256, 0, stream>>>(W, a, gcur, Btg);
    k_fused<<<EBLK + PBLK, 256, 0, stream>>>(h, Btg, Wb, a, ab, src, dst,
                                             gcur, sb, Whb, es, ed);
    k_bucket<<<NBK * 4, 256, 0, stream>>>(sb, gcur, Whb, es, ed, out);
}

// Round 13
// 186.850 us; speedup vs baseline: 1.1360x; 1.0677x over previous
//
#include <hip/hip_runtime.h>
#include <hip/hip_bf16.h>
#include <math.h>

#define N_NODES 100000
#define N_EDGES 1600000
#define NF 128
#define NH 4
#define ND 16
#define GAT_ALPHA 0.2f

#define BSHIFT 8                      // bucket = dst >> 8 (256 nodes per bucket)
#define NBK 391                       // ceil(100000 / 256)
#define CAPB 5120                     // slab capacity per bucket
#define CAPQ 1280                     // quarter-bucket LDS list capacity
#define EPB 8192                      // edges per placement block
#define EBLK 196                      // placement blocks
#define PBLK 391                      // projection blocks (4 tiles each, PARALLEL)
#define NTILES ((N_NODES + 63) / 64)  // 1563

typedef __attribute__((ext_vector_type(8))) __bf16 bf16x8;
typedef __attribute__((ext_vector_type(4))) float f32x4;

#define PADK 136                      // bf16 row stride (272B), breaks bank stride

// ---------------------------------------------------------------------------
// k_prep: one-time B-table build + gcur zeroing.
// Btg layout (compact [80][128] bf16): rows 0..63 = W^T per head,
// rows 64+hh = W·a1, rows 72+hh = W·a2, rows 68..71 / 76..79 = zero.
// ---------------------------------------------------------------------------
__global__ __launch_bounds__(256) void k_prep(
    const float* __restrict__ W, const float* __restrict__ a,
    int* __restrict__ gcur, __hip_bfloat16* __restrict__ Btg)
{
    const int hh = blockIdx.x;        // 0..3 (one block per head)
    const int t = threadIdx.x;

    if (hh == 0)
        for (int i = t; i < 512; i += 256) gcur[i] = 0;

    for (int idx = t; idx < 2048; idx += 256) {
        int d = idx & 15, f = idx >> 4;
        Btg[(hh * 16 + d) * 128 + f] =
            __float2bfloat16(W[hh * (NF * ND) + f * ND + d]);
    }
    for (int idx = t; idx < 256; idx += 256) {
        int f = idx & 127, which = idx >> 7;
        float s = 0.f;
        #pragma unroll
        for (int d = 0; d < 16; d++)
            s = fmaf(W[hh * (NF * ND) + f * ND + d], a[hh * 32 + which * 16 + d], s);
        Btg[(64 + which * 8 + hh) * 128 + f] = __float2bfloat16(s);
    }
    for (int idx = t; idx < 256; idx += 256) {
        int f = idx & 127, which = idx >> 7;
        Btg[(68 + which * 8 + hh) * 128 + f] = __float2bfloat16(0.f);
    }
}

// ---------------------------------------------------------------------------
// Fused kernel, 1024 threads/block (16 waves), role by blockIdx:
//   blocks [0, EBLK)      : bucket placement into 256-node slabs
//   blocks [EBLK, EBLK+PBLK): MFMA projection — the block's 4 tiles are
//   computed by 4 CONCURRENT 256-thread groups (not serially), tripling
//   resident waves/CU for the latency-bound h reads.  One Bt staging copy
//   per block (amortized over 4 tiles), same as the proven round-6 config.
// ---------------------------------------------------------------------------
__global__ __launch_bounds__(1024) void k_fused(
    const float* __restrict__ h, const __hip_bfloat16* __restrict__ Btg,
    const float* __restrict__ Wb, const float* __restrict__ a,
    const float* __restrict__ ab, const int* __restrict__ src,
    const int* __restrict__ dst, int* __restrict__ gcur,
    uint* __restrict__ sb, __hip_bfloat16* __restrict__ Whb,
    float* __restrict__ es, float* __restrict__ ed)
{
    __shared__ __align__(16) char smem[80 * PADK * 2];      // 21.8 KB union

    const int tid = threadIdx.x;

    if (blockIdx.x < EBLK) {
        // ---------------- role: bucket placement ------------------------
        int* hist = (int*)smem;            // [NBK]
        int* cur  = hist + NBK;            // [NBK]
        const int base = blockIdx.x * EPB;
        const int lim = min(EPB, N_EDGES - base);

        for (int i = tid; i < NBK; i += 1024) hist[i] = 0;
        __syncthreads();
        for (int i = tid; i < lim; i += 1024)
            atomicAdd(&hist[dst[base + i] >> BSHIFT], 1);
        __syncthreads();
        for (int i = tid; i < NBK; i += 1024) {
            int v = hist[i];
            cur[i] = v ? atomicAdd(&gcur[i], v) : 0;
        }
        __syncthreads();
        for (int i = tid; i < lim; i += 1024) {
            int d = dst[base + i];
            int bk = d >> BSHIFT;
            int pos = atomicAdd(&cur[bk], 1);            // LDS returning atomic
            if (pos < CAPB)
                sb[bk * CAPB + pos] = (uint)(src[base + i] | ((d & 255) << 17));
        }
        return;
    }

    // ------------------- role: MFMA projection --------------------------
    __hip_bfloat16* Bt = (__hip_bfloat16*)smem;   // [80][PADK]
    const int pb = blockIdx.x - EBLK;    // 0..PBLK-1
    const int grp = tid >> 8;            // 0..3: which of the block's 4 tiles
    const int gtid = tid & 255;          // thread within tile group
    const int wv = gtid >> 6;            // wave within tile (0..3)
    const int l = tid & 63;
    const int m = l & 15;
    const int quad = l >> 4;

    // stage B: vectorized copy of precomputed table (1280 float4)
    for (int c = tid; c < 80 * 128 / 8; c += 1024) {
        int row = c >> 4, col = (c & 15) * 8;
        *(float4*)&Bt[row * PADK + col] = ((const float4*)Btg)[c];
    }

    float wb4[4];
    #pragma unroll
    for (int t = 0; t < 4; t++) wb4[t] = Wb[t * 16 + m];
    float eb = 0.f;
    if (m < 4) {
        #pragma unroll
        for (int d = 0; d < 16; d++) eb = fmaf(Wb[m * 16 + d], a[m * 32 + d], eb);
    } else if (m >= 8 && m < 12) {
        int hh = m - 8;
        #pragma unroll
        for (int d = 0; d < 16; d++)
            eb = fmaf(Wb[hh * 16 + d], a[hh * 32 + 16 + d], eb);
        eb += ab[hh];
    }
    __syncthreads();   // Bt visible; no further barriers

    const int tile = pb + grp * PBLK;    // 4 parallel tiles: pb, pb+391, ...
    if (tile < NTILES) {
        const int node = tile * 64 + wv * 16 + m;   // A row this lane serves
        const bool ok = node < N_NODES;
        const float4* hrow = (const float4*)(h + (size_t)(ok ? node : 0) * NF);

        f32x4 acc[5];
        #pragma unroll
        for (int t = 0; t < 5; t++) acc[t] = (f32x4){0.f, 0.f, 0.f, 0.f};

        #pragma unroll
        for (int kk = 0; kk < 4; kk++) {
            // A-frag direct from global: cols kk*32 + quad*8 .. +8
            bf16x8 af;
            if (ok) {
                float4 v0 = hrow[kk * 8 + quad * 2];
                float4 v1 = hrow[kk * 8 + quad * 2 + 1];
                af[0] = (__bf16)v0.x; af[1] = (__bf16)v0.y;
                af[2] = (__bf16)v0.z; af[3] = (__bf16)v0.w;
                af[4] = (__bf16)v1.x; af[5] = (__bf16)v1.y;
                af[6] = (__bf16)v1.z; af[7] = (__bf16)v1.w;
            } else {
                #pragma unroll
                for (int j = 0; j < 8; j++) af[j] = (__bf16)0.f;
            }
            #pragma unroll
            for (int t = 0; t < 5; t++) {
                bf16x8 bf = *(const bf16x8*)&Bt[(t * 16 + m) * PADK + kk * 32 + quad * 8];
                acc[t] = __builtin_amdgcn_mfma_f32_16x16x32_bf16(af, bf, acc[t], 0, 0, 0);
            }
        }

        // epilogue: D layout col=lane&15, row=quad*4+reg
        const int nodeb = tile * 64 + wv * 16 + quad * 4;
        #pragma unroll
        for (int r = 0; r < 4; r++) {
            int n = nodeb + r;
            if (n < N_NODES) {
                #pragma unroll
                for (int t = 0; t < 4; t++)
                    Whb[n * 64 + t * 16 + m] = __float2bfloat16(acc[t][r] + wb4[t]);
                float ev = acc[4][r] + eb;
                if (m < 4) es[n * 4 + m] = ev;
                else if (m >= 8 && m < 12) ed[n * 4 + (m - 8)] = ev;
            }
        }
    }
}

// ---------------------------------------------------------------------------
// One block per QUARTER of a 256-node bucket (64 dst nodes, 256 thr, 4 waves,
// ~10 KB LDS): streams the full bucket slab, filters its quarter into a
// node-grouped LDS list (int atomics), then sequential-FMA per-node gather.
// ROUND-6 EXACT SOURCE (measured 58.7-59.7 µs across 4 runs; all
// restructures regressed — local optimum).
// ---------------------------------------------------------------------------
__global__ __launch_bounds__(256) void k_bucket(
    const uint* __restrict__ sb, const int* __restrict__ gcur,
    const __hip_bfloat16* __restrict__ Whb, const float* __restrict__ es,
    const float* __restrict__ ed, float* __restrict__ out)
{
    __shared__ int ssl[CAPQ];          // 5.1 KB node-grouped src list
    __shared__ int ncnt[64];           // per-node degree
    __shared__ int noff[64];           // per-node start in ssl
    __shared__ int ncur[64];           // scatter cursors
    __shared__ float pu_all[4][256];   // 4 KB per-wave p staging

    const int b  = blockIdx.x >> 2;    // bucket
    const int qt = blockIdx.x & 3;     // quarter
    const int t  = threadIdx.x;
    const int l  = t & 63;
    const int wid = t >> 6;            // 0..3

    const int ebase = b * CAPB;
    const int ecnt = min(gcur[b], CAPB);
    const int dlo = qt << 6;           // 0,64,128,192

    if (t < 64) ncnt[t] = 0;
    __syncthreads();

    // ---- count this quarter's nodes (filter; int LDS atomics) ----
    for (int i = t; i < ecnt; i += 256) {
        int dn = (int)(sb[ebase + i] >> 17) - dlo;
        if ((unsigned)dn < 64u) atomicAdd(&ncnt[dn], 1);
    }
    __syncthreads();

    // ---- inclusive scan of ncnt[0..63] by wave 0 ----
    if (t < 64) {
        int v = ncnt[t];
        int x = v;
        #pragma unroll
        for (int o = 1; o < 64; o <<= 1) {
            int y = __shfl_up(x, o);
            if (l >= o) x += y;
        }
        noff[t] = x - v;
        ncur[t] = x - v;
    }
    __syncthreads();

    // ---- scatter matching slab entries into node-grouped LDS list ----
    for (int i = t; i < ecnt; i += 256) {
        uint v = sb[ebase + i];
        int dn = (int)(v >> 17) - dlo;
        if ((unsigned)dn < 64u) {
            int pos = atomicAdd(&ncur[dn], 1);   // int returning LDS atomic
            if (pos < CAPQ) ssl[pos] = (int)(v & 0x1FFFFu);
        }
    }
    __syncthreads();

    // ---- gather phase: 4 waves x 16 nodes, sequential-FMA inner loop ----
    const int r = l & 15;              // lane-in-quarter: dims 4r..4r+3
    const int q = l >> 4;              // quarter-wave = which edge of the 4-group
    const int hh = r >> 2;             // head of dims 4r..4r+3
    const float4* es4 = (const float4*)es;
    const uint2* Wu2 = (const uint2*)Whb;
    float* pu = &pu_all[wid][0];
    const float* pu_q = pu + q * 4 + hh;

    for (int k = 0; k < 16; k++) {
        const int ln = wid * 16 + k;
        const int node = b * 256 + dlo + ln;
        if (node >= N_NODES) break;    // nodes ascend within wave

        int start = noff[ln];
        int deg = ncnt[ln];
        if (start >= CAPQ) deg = 0;            // overflow-drop safety
        else deg = min(deg, CAPQ - start);

        const float4 edv = ((const float4*)ed)[node];

        float acc0 = 0.f, acc1 = 0.f, acc2 = 0.f, acc3 = 0.f, den = 0.f;

        for (int bst = 0; bst < deg; bst += 64) {
            int nchunk = min(64, deg - bst);

            float4 p4 = make_float4(0.f, 0.f, 0.f, 0.f);
            if (l < nchunk) {
                int sl = ssl[start + bst + l];
                float4 esv = es4[sl];
                float x;
                x = esv.x + edv.x; p4.x = __expf(fmaxf(x, GAT_ALPHA * x));
                x = esv.y + edv.y; p4.y = __expf(fmaxf(x, GAT_ALPHA * x));
                x = esv.z + edv.z; p4.z = __expf(fmaxf(x, GAT_ALPHA * x));
                x = esv.w + edv.w; p4.w = __expf(fmaxf(x, GAT_ALPHA * x));
            }
            ((float4*)pu)[l] = p4;     // zero-padded tail
            // single wave owns pu: wave-internal lgkm ordering, no barrier

            const int last = start + deg - 1;
            #pragma unroll 4
            for (int jj = 0; jj < nchunk; jj += 4) {
                int ee = min(start + bst + jj + q, last);  // clamp: tail p==0
                int s = ssl[ee];
                float p = pu_q[jj * 4];
                uint2 v = Wu2[s * 16 + r];
                acc0 = fmaf(p, __uint_as_float(v.x << 16), acc0);
                acc1 = fmaf(p, __uint_as_float(v.x & 0xffff0000u), acc1);
                acc2 = fmaf(p, __uint_as_float(v.y << 16), acc2);
                acc3 = fmaf(p, __uint_as_float(v.y & 0xffff0000u), acc3);
                den += p;
            }
        }

        acc0 += __shfl_xor(acc0, 16); acc1 += __shfl_xor(acc1, 16);
        acc2 += __shfl_xor(acc2, 16); acc3 += __shfl_xor(acc3, 16);
        den  += __shfl_xor(den, 16);
        acc0 += __shfl_xor(acc0, 32); acc1 += __shfl_xor(acc1, 32);
        acc2 += __shfl_xor(acc2, 32); acc3 += __shfl_xor(acc3, 32);
        den  += __shfl_xor(den, 32);

        if (q == 0) {
            float rr = 1.0f / fmaxf(den, 1e-9f);   // deg==0 -> 0, matches ref
            ((float4*)out)[node * 16 + r] =
                make_float4(acc0 * rr, acc1 * rr, acc2 * rr, acc3 * rr);
        }
    }
}

// ---------------------------------------------------------------------------
extern "C" void kernel_launch(void* const* d_in, const int* in_sizes, int n_in,
                              void* d_out, int out_size, void* d_ws, size_t ws_size,
                              hipStream_t stream)
{
    const float* h  = (const float*)d_in[0];
    const float* W  = (const float*)d_in[1];
    const float* Wb = (const float*)d_in[2];
    const float* a  = (const float*)d_in[3];
    const float* ab = (const float*)d_in[4];
    const int* src  = (const int*)d_in[5];
    const int* dst  = (const int*)d_in[6];
    float* out = (float*)d_out;

    char* w = (char*)d_ws;
    __hip_bfloat16* Whb = (__hip_bfloat16*)w; w += (size_t)N_NODES * 64 * 2;  // 12.8 MB
    float* es      = (float*)w;  w += (size_t)N_NODES * 4 * 4;     // 1.6 MB
    float* ed      = (float*)w;  w += (size_t)N_NODES * 4 * 4;     // 1.6 MB
    uint* sb       = (uint*)w;   w += (size_t)NBK * CAPB * 4;      // 8.0 MB
    int* gcur      = (int*)w;    w += 512 * 4;
    __hip_bfloat16* Btg = (__hip_bfloat16*)w; w += 80 * 128 * 2;   // 20.5 KB
    // total ~24 MB

    k_prep<<<4, 256, 0, stream>>>(W, a, gcur, Btg);
    k_fused<<<EBLK + PBLK, 1024, 0, stream>>>(h, Btg, Wb, a, ab, src, dst,
                                              gcur, sb, Whb, es, ed);
    k_bucket<<<NBK * 4, 256, 0, stream>>>(sb, gcur, Whb, es, ed, out);
}